// Round 4
// baseline (327.194 us; speedup 1.0000x reference)
//
#include <hip/hip_runtime.h>

// Modular readout: 8 modules, each h = relu(x_m @ W1_m^T + b1_m); y_m = h @ W2_m^T + b2_m
// x [8192,4096] fp32; W1 [4096,4096] fp32 block-diag (8x 512x512); W2 [80,4096] fp32 block-diag
// out [8192,80] fp32 row-major (module-major columns).
//
// R4: R2/R3 identical at ~97 us despite occupancy 2x => limiter was per-iter W1 re-staging +
// barrier-drain latency over short 16-iter K-loops. Fix: W1 quarter-block LDS-RESIDENT.
//  - block owns (module m, hidden quarter q, 512 batch rows). W1q [128][512] bf16 in LDS (130 KB,
//    stride 520 shorts -> conflict-free), loaded once from fp32 W1. Zero workspace.
//  - K-loop: only x staged (fp32->bf16 in reg), 20 KB double-buffer, ONE barrier/iter, 128 iters/block.
//  - 8 waves, wave tile 64x32 (acc[4][2]): LDS 48 KB/iter (375 cyc) vs MFMA 310 cyc -> near-balanced.
//  - layer 2 fused per 128-row tile: h -> ldsH [64][136] (aliased on x-dbuf), hoisted W2 frags,
//    atomicAdd into out pre-filled with b2 by init kernel.

#define NMOD 8
#define DIM 512
#define OSZ 10
#define BATCH 8192
#define D_IN 4096
#define D_OUT 80
#define QN 128            // hidden rows per block (quarter of module)
#define MT 128            // batch rows per M-tile
#define RT 4              // M-tiles per block -> 512 rows/block
#define BK 32

#define WSTRIDE 520       // ldsW row stride (shorts): 1040 B, quad-adv 65 == 1 mod 8 -> conflict-free
#define XSTRIDE 40        // ldsX row stride: 80 B, quad-adv 5 -> conflict-free
#define HSTRIDE 136       // ldsH row stride: 272 B, quad-adv 17 == 1 mod 8 -> conflict-free
#define LDSW_SZ 66560     // 128*520
#define LDSX_SZ 5120      // 128*40 per buffer

typedef __attribute__((ext_vector_type(8))) short short8;   // 8 bf16 MFMA A/B frag
typedef __attribute__((ext_vector_type(4))) float float4v;  // MFMA C/D frag

__device__ __forceinline__ unsigned short f2bf(float f) {
    unsigned int u = __builtin_bit_cast(unsigned int, f);
    u += 0x7fffu + ((u >> 16) & 1u);   // RNE
    return (unsigned short)(u >> 16);
}

__device__ __forceinline__ short8 cvt8(float4 a, float4 b) {
    short8 r;
    r[0] = (short)f2bf(a.x); r[1] = (short)f2bf(a.y); r[2] = (short)f2bf(a.z); r[3] = (short)f2bf(a.w);
    r[4] = (short)f2bf(b.x); r[5] = (short)f2bf(b.y); r[6] = (short)f2bf(b.z); r[7] = (short)f2bf(b.w);
    return r;
}

// ------- init: out = broadcast b2 (atomicAdd accumulation base) -------
__global__ void init_out_kernel(const float* __restrict__ b2, float* __restrict__ out) {
    int idx = blockIdx.x * 256 + threadIdx.x;            // 2560*256 = 655360 = 8192*80
    out[idx] = b2[idx % D_OUT];
}

// ---------------- fused persistent-W1 kernel ----------------
// grid 512: bid = r*32 + q*8 + m (m -> XCD round-robin). block 512 threads (8 waves).
// Wave (wm = w>>2, wn = w&3): rows [wm*64, +64), hidden cols [wn*32, +32) of the tile.
__global__ __launch_bounds__(512, 2)
void fused_kernel(const float* __restrict__ x, const float* __restrict__ W1,
                  const float* __restrict__ b1, const float* __restrict__ W2,
                  float* __restrict__ out) {
    __shared__ ushort smem[76800];                 // 150 KB
    ushort* ldsW = smem;                           // [128][520]
    ushort* ldsX = smem + LDSW_SZ;                 // 2 x [128][40]
    ushort* ldsH = smem + LDSW_SZ;                 // [64][136] (alias, barrier-disciplined)

    const int tid  = threadIdx.x;
    const int wave = tid >> 6;
    const int lane = tid & 63;
    const int r16  = lane & 15;
    const int kq   = lane >> 4;
    const int wm   = wave >> 2;
    const int wn   = wave & 3;

    const int bid    = blockIdx.x;
    const int m      = bid & 7;
    const int q      = (bid >> 3) & 3;
    const int blkRow = (bid >> 5) * (MT * RT);

    // ---- load W1 quarter [128][512] fp32 -> bf16 LDS, once ----
    {
        const int row = tid >> 2, seg = tid & 3;
        const float* src = W1 + (size_t)(m * DIM + q * QN + row) * D_IN + m * DIM + seg * 128;
        ushort* dst = ldsW + row * WSTRIDE + seg * 128;
#pragma unroll 4
        for (int j = 0; j < 16; j++) {
            float4 a = *(const float4*)(src + j * 8);
            float4 b = *(const float4*)(src + j * 8 + 4);
            *(short8*)(dst + j * 8) = cvt8(a, b);
        }
    }

    // ---- hoist W2 quarter frags (layer-2 B operand; rows >= OSZ are zero) ----
    short8 w2f[4];
    {
        const float* w2base = W2 + (size_t)(m * OSZ + r16) * D_IN + m * DIM + q * QN;
#pragma unroll
        for (int kc = 0; kc < 4; kc++) {
            if (r16 < OSZ) {
                const float* p = w2base + (kc * 4 + kq) * 8;
                w2f[kc] = cvt8(*(const float4*)p, *(const float4*)(p + 4));
            } else {
                w2f[kc] = (short8){0, 0, 0, 0, 0, 0, 0, 0};
            }
        }
    }

    float b1v[2];
#pragma unroll
    for (int nt = 0; nt < 2; nt++)
        b1v[nt] = b1[m * DIM + q * QN + wn * 32 + nt * 16 + r16];

    const int srow = tid >> 2;                     // staging row 0..127
    const int sc   = tid & 3;                      // staging k-chunk 0..3

    for (int rt = 0; rt < RT; rt++) {
        const int rowBase = blkRow + rt * MT;
        const float* xsrc = x + (size_t)(rowBase + srow) * D_IN + m * DIM + sc * 8;

        float4v acc[4][2];
#pragma unroll
        for (int i = 0; i < 4; i++)
#pragma unroll
            for (int j = 0; j < 2; j++) acc[i][j] = (float4v){0.f, 0.f, 0.f, 0.f};

        // prologue: stage kk=0 into buf0 (also covers W-load/ldsH reuse via loop-top barrier)
        {
            float4 a = *(const float4*)(xsrc);
            float4 b = *(const float4*)(xsrc + 4);
            *(short8*)(ldsX + srow * XSTRIDE + sc * 8) = cvt8(a, b);
        }

        for (int kk = 0; kk < DIM / BK; kk++) {
            __syncthreads();                       // buf[kk&1] ready; prev writers done
            float4 na, nb;
            const bool pf = (kk < DIM / BK - 1);
            if (pf) {                              // prefetch next x chunk (uniform branch)
                const float* p = xsrc + (kk + 1) * BK;
                na = *(const float4*)p;
                nb = *(const float4*)(p + 4);
            }
            const ushort* xb = ldsX + (kk & 1) * LDSX_SZ;
            short8 aF[4], bF[2];
#pragma unroll
            for (int mt = 0; mt < 4; mt++)
                aF[mt] = *(const short8*)(xb + (wm * 64 + mt * 16 + r16) * XSTRIDE + kq * 8);
#pragma unroll
            for (int nt = 0; nt < 2; nt++)
                bF[nt] = *(const short8*)(ldsW + (wn * 32 + nt * 16 + r16) * WSTRIDE + (kk * 4 + kq) * 8);
#pragma unroll
            for (int mt = 0; mt < 4; mt++)
#pragma unroll
                for (int nt = 0; nt < 2; nt++)
                    acc[mt][nt] = __builtin_amdgcn_mfma_f32_16x16x32_bf16(aF[mt], bF[nt], acc[mt][nt], 0, 0, 0);
            if (pf)                                // write next buffer (other region; next barrier syncs)
                *(short8*)(ldsX + ((kk + 1) & 1) * LDSX_SZ + srow * XSTRIDE + sc * 8) = cvt8(na, nb);
        }

        // ---- epilogue: bias+relu, two 64-row halves through ldsH, fused layer 2 ----
        for (int hh = 0; hh < 2; hh++) {
            __syncthreads();                       // K-loop frag reads / prev half reads complete
            if (wm == hh) {
#pragma unroll
                for (int mt = 0; mt < 4; mt++)
#pragma unroll
                    for (int nt = 0; nt < 2; nt++)
#pragma unroll
                        for (int reg = 0; reg < 4; reg++) {
                            float v = acc[mt][nt][reg] + b1v[nt];
                            v = v > 0.f ? v : 0.f;
                            ldsH[(mt * 16 + kq * 4 + reg) * HSTRIDE + wn * 32 + nt * 16 + r16] = f2bf(v);
                        }
            }
            __syncthreads();
            if (wave < 4) {                        // 4 waves x 16 rows: y[64][10] partial
                float4v acc2 = (float4v){0.f, 0.f, 0.f, 0.f};
#pragma unroll
                for (int kc = 0; kc < 4; kc++) {
                    short8 hA = *(const short8*)(ldsH + (wave * 16 + r16) * HSTRIDE + (kc * 4 + kq) * 8);
                    acc2 = __builtin_amdgcn_mfma_f32_16x16x32_bf16(hA, w2f[kc], acc2, 0, 0, 0);
                }
                if (r16 < OSZ) {
#pragma unroll
                    for (int reg = 0; reg < 4; reg++) {
                        const int grow = rowBase + hh * 64 + wave * 16 + kq * 4 + reg;
                        atomicAdd(out + (size_t)grow * D_OUT + m * OSZ + r16, acc2[reg]);
                    }
                }
            }
        }
        __syncthreads();                           // ldsH reads done before next rt's staging
    }
}

extern "C" void kernel_launch(void* const* d_in, const int* in_sizes, int n_in,
                              void* d_out, int out_size, void* d_ws, size_t ws_size,
                              hipStream_t stream) {
    const float* x  = (const float*)d_in[0];
    const float* W1 = (const float*)d_in[1];
    const float* b1 = (const float*)d_in[2];
    const float* W2 = (const float*)d_in[3];
    const float* b2 = (const float*)d_in[4];
    float* out = (float*)d_out;

    init_out_kernel<<<dim3(2560), dim3(256), 0, stream>>>(b2, out);
    fused_kernel<<<dim3(512), dim3(512), 0, stream>>>(x, W1, b1, W2, out);
}

// Round 5
// 258.990 us; speedup vs baseline: 1.2633x; 1.2633x over previous
//
#include <hip/hip_runtime.h>

// Modular readout: 8 modules, each h = relu(x_m @ W1_m^T + b1_m); y_m = h @ W2_m^T + b2_m
// x [8192,4096] fp32; W1 [4096,4096] fp32 block-diag (8x 512x512); W2 [80,4096] fp32 block-diag
// out [8192,80] fp32 row-major (module-major columns).
//
// R5: R4 was latency-serialized (512 iters x ~375cyc) AND LDS-pipe-bound (64x32 wave tile).
//  - Back to streaming (R3) but wave tile 128x64: 12 ds_read_b128 (144cyc) vs 32 MFMA (155cyc) balanced.
//  - Block 256thr/4waves, tile 128x256 (hidden half); LDS 53KB -> 2 blocks/CU overlap.
//  - ONE barrier/iter; prefetch issued AFTER barrier (x->regs, W1 bf16 via global_load_lds),
//    consumed ~600cyc later at end of compute: latency hidden, vmcnt(0) pre-barrier drain is ~free.
//  - Conflict-free LDS: A stride 40 (col16=5r+kq distinct mod 8); B unpadded 32 + src-XOR
//    slot=kq^((row>>1)&3); ldsH stride 264 (33 col16 -> r16+c distinct).
//  - bid%8 = module -> XCD affinity: W1 module strip stays in that XCD's L2; x half-pairs adjacent.
//  - Layer 2 fused per 64-row half via ldsH; partials atomicAdd into out pre-filled with b2.

#define NMOD 8
#define DIM 512
#define OSZ 10
#define BATCH 8192
#define D_IN 4096
#define D_OUT 80
#define BM 128
#define BN 256
#define BK 32

#define ASTRIDE 40        // ldsA row stride (shorts); 80B, 16B-aligned, 5 col16/row -> conflict-free
#define HSTRIDE 264       // ldsH row stride (shorts); 528B = 33*16 -> aligned + conflict-free
#define LDSA_SZ 5120      // 128*40 shorts per buffer
#define LDSB_SZ 8192      // 256*32 shorts per buffer (unpadded: DMA needs lane-contiguous dst)

typedef __attribute__((ext_vector_type(8))) short short8;   // 8 bf16 MFMA A/B frag
typedef __attribute__((ext_vector_type(4))) float float4v;  // MFMA C/D frag

__device__ __forceinline__ unsigned short f2bf(float f) {
    unsigned int u = __builtin_bit_cast(unsigned int, f);
    u += 0x7fffu + ((u >> 16) & 1u);   // RNE
    return (unsigned short)(u >> 16);
}

__device__ __forceinline__ short8 cvt8(float4 a, float4 b) {
    short8 r;
    r[0] = (short)f2bf(a.x); r[1] = (short)f2bf(a.y); r[2] = (short)f2bf(a.z); r[3] = (short)f2bf(a.w);
    r[4] = (short)f2bf(b.x); r[5] = (short)f2bf(b.y); r[6] = (short)f2bf(b.z); r[7] = (short)f2bf(b.w);
    return r;
}

// ------- init: out = broadcast b2 (atomicAdd accumulation base) -------
__global__ void init_out_kernel(const float* __restrict__ b2, float* __restrict__ out) {
    int idx = blockIdx.x * 256 + threadIdx.x;            // 2560*256 = 655360 = 8192*80
    out[idx] = b2[idx % D_OUT];
}

// ------- tier B: gather W1 diag blocks -> w1b[8][512][512] bf16 (4 MB) -------
__global__ void cvt_w_kernel(const float* __restrict__ W1, ushort* __restrict__ w1b) {
    int j = blockIdx.x * 256 + threadIdx.x;              // 2048*256 = 524288 float4 jobs
    int mm = j >> 16, rem = j & 65535, r = rem >> 7, c4 = rem & 127;
    float4 v = *(const float4*)(W1 + (size_t)(mm * DIM + r) * D_IN + mm * DIM + c4 * 4);
    *(ushort4*)(w1b + (size_t)mm * DIM * DIM + r * DIM + c4 * 4) =
        make_ushort4(f2bf(v.x), f2bf(v.y), f2bf(v.z), f2bf(v.w));
}

// ---------------- fused kernel ----------------
// grid 1024: bid = tile*16 + half*8 + m. block 256 (4 waves), wave w: hidden cols [w*64,+64),
// all 128 batch rows (acc[8][4] = 128 regs).
// LDS 53248 B: A0@0, A1@10240, B0@20480, B1@36864 (bytes); ldsH [64][264] @0 (33792, aliased).
template <bool WPRE>
__global__ __launch_bounds__(256, 2)
void fused_kernel(const float* __restrict__ x, const float* __restrict__ W1,
                  const ushort* __restrict__ w1b, const float* __restrict__ b1,
                  const float* __restrict__ W2, const float* __restrict__ b2,
                  float* __restrict__ out) {
    __shared__ __attribute__((aligned(16))) ushort smem[26624];   // 53248 B
    ushort* ldsA0 = smem;
    ushort* ldsA1 = smem + LDSA_SZ;
    ushort* ldsB0 = smem + 2 * LDSA_SZ;
    ushort* ldsB1 = smem + 2 * LDSA_SZ + LDSB_SZ;
    ushort* ldsH  = smem;                                 // [64][264] epilogue alias

    const int tid  = threadIdx.x;
    const int wave = tid >> 6;
    const int lane = tid & 63;
    const int r16  = lane & 15;
    const int kq   = lane >> 4;

    const int bid     = blockIdx.x;
    const int m       = bid & 7;                          // module -> XCD round-robin
    const int half    = (bid >> 3) & 1;                   // hidden half [half*256,+256)
    const int rowBase = (bid >> 4) * BM;

    const float*  xsrc = x + (size_t)rowBase * D_IN + m * DIM;                    // +row*4096
    const ushort* w1h  = w1b + (size_t)m * DIM * DIM + (size_t)half * BN * DIM;   // bf16 [256][512]
    const float*  w1f  = W1 + (size_t)(m * DIM + half * BN) * D_IN + m * DIM;     // fp32 fallback

    // staging thread mapping
    const int arow = tid >> 1;            // x: row 0..127
    const int ah   = tid & 1;             // x: 16-float half of the 32-float k-slice
    const int brow = tid >> 2;            // W: row within 64-row round
    const int bc   = tid & 3;             // W: 16B chunk 0..3

    float4v acc[8][4];
#pragma unroll
    for (int i = 0; i < 8; i++)
#pragma unroll
        for (int j = 0; j < 4; j++) acc[i][j] = (float4v){0.f, 0.f, 0.f, 0.f};

    // ---- prologue: stage k-slice 0 into A0/B0 ----
    if (WPRE) {
#pragma unroll
        for (int r = 0; r < 4; r++) {
            const int row = r * 64 + brow;
            const int f   = (row >> 1) & 3;
            __builtin_amdgcn_global_load_lds(
                (const __attribute__((address_space(1))) void*)(w1h + (size_t)row * DIM + (bc ^ f) * 8),
                (__attribute__((address_space(3))) void*)(ldsB0 + row * BK + bc * 8), 16, 0, 0);
        }
    } else {
#pragma unroll
        for (int r = 0; r < 4; r++) {
            const int row = r * 64 + brow;
            const int f   = (row >> 1) & 3;
            const float* p = w1f + (size_t)row * D_IN + bc * 8;   // read chunk bc (coalesced)
            *(short8*)(ldsB0 + row * BK + (bc ^ f) * 8) = cvt8(*(const float4*)p, *(const float4*)(p + 4));
        }
    }
    {
        const float* p = xsrc + (size_t)arow * D_IN + ah * 16;
        float4 a0 = *(const float4*)p, a1 = *(const float4*)(p + 4);
        float4 a2 = *(const float4*)(p + 8), a3 = *(const float4*)(p + 12);
        *(short8*)(ldsA0 + arow * ASTRIDE + ah * 16)     = cvt8(a0, a1);
        *(short8*)(ldsA0 + arow * ASTRIDE + ah * 16 + 8) = cvt8(a2, a3);
    }

    for (int kk = 0; kk < DIM / BK; kk++) {
        __syncthreads();                                  // cur buffers ready (drains DMA + writes)
        ushort* Ac = (kk & 1) ? ldsA1 : ldsA0;
        ushort* Bc = (kk & 1) ? ldsB1 : ldsB0;
        ushort* An = (kk & 1) ? ldsA0 : ldsA1;
        ushort* Bn = (kk & 1) ? ldsB0 : ldsB1;

        float4 xr0, xr1, xr2, xr3;
        const bool pf = (kk < DIM / BK - 1);
        if (pf) {                                         // prefetch next k-slice (in flight ~compute)
            const int k0n = (kk + 1) * BK;
            if (WPRE) {
#pragma unroll
                for (int r = 0; r < 4; r++) {
                    const int row = r * 64 + brow;
                    const int f   = (row >> 1) & 3;
                    __builtin_amdgcn_global_load_lds(
                        (const __attribute__((address_space(1))) void*)(w1h + (size_t)row * DIM + k0n + (bc ^ f) * 8),
                        (__attribute__((address_space(3))) void*)(Bn + row * BK + bc * 8), 16, 0, 0);
                }
            }
            const float* p = xsrc + (size_t)arow * D_IN + kk * BK + BK + ah * 16;
            xr0 = *(const float4*)p;     xr1 = *(const float4*)(p + 4);
            xr2 = *(const float4*)(p + 8); xr3 = *(const float4*)(p + 12);
        }

        short8 aF[8], bF[4];
#pragma unroll
        for (int mt = 0; mt < 8; mt++)
            aF[mt] = *(const short8*)(Ac + (mt * 16 + r16) * ASTRIDE + kq * 8);
#pragma unroll
        for (int nt = 0; nt < 4; nt++) {
            const int row = wave * 64 + nt * 16 + r16;
            bF[nt] = *(const short8*)(Bc + row * BK + (kq ^ ((row >> 1) & 3)) * 8);
        }
#pragma unroll
        for (int mt = 0; mt < 8; mt++)
#pragma unroll
            for (int nt = 0; nt < 4; nt++)
                acc[mt][nt] = __builtin_amdgcn_mfma_f32_16x16x32_bf16(aF[mt], bF[nt], acc[mt][nt], 0, 0, 0);

        if (pf) {                                         // x regs ~landed by now; write next A buf
            *(short8*)(An + arow * ASTRIDE + ah * 16)     = cvt8(xr0, xr1);
            *(short8*)(An + arow * ASTRIDE + ah * 16 + 8) = cvt8(xr2, xr3);
            if (!WPRE) {
#pragma unroll
                for (int r = 0; r < 4; r++) {
                    const int row = r * 64 + brow;
                    const int f   = (row >> 1) & 3;
                    const float* p = w1f + (size_t)row * D_IN + kk * BK + BK + bc * 8;
                    *(short8*)(Bn + row * BK + (bc ^ f) * 8) = cvt8(*(const float4*)p, *(const float4*)(p + 4));
                }
            }
        }
    }

    float b1v[4];
#pragma unroll
    for (int nt = 0; nt < 4; nt++)
        b1v[nt] = b1[m * DIM + half * BN + wave * 64 + nt * 16 + r16];

    // ---- epilogue: two 64-row halves; h -> ldsH (bias+relu bf16); fused layer-2 partial ----
    for (int hh = 0; hh < 2; hh++) {
        __syncthreads();                                  // K-loop frag reads / prev layer-2 reads done
#pragma unroll
        for (int mt2 = 0; mt2 < 4; mt2++) {
            const int mt = hh * 4 + mt2;
#pragma unroll
            for (int nt = 0; nt < 4; nt++) {
#pragma unroll
                for (int reg = 0; reg < 4; reg++) {
                    float v = acc[mt][nt][reg] + b1v[nt];
                    v = v > 0.f ? v : 0.f;
                    const int lr  = mt2 * 16 + kq * 4 + reg;          // local batch row 0..63
                    const int col = wave * 64 + nt * 16 + r16;        // hidden col within half
                    ldsH[lr * HSTRIDE + col] = f2bf(v);
                }
            }
        }
        __syncthreads();

        // layer 2 partial: y[64][10] += h[64][256] @ W2_half^T; 4 waves x 16 rows; W2 inline fp32->bf16
        {
            float4v acc2 = (float4v){0.f, 0.f, 0.f, 0.f};
            const int hrow = wave * 16 + r16;
            const float* w2row = W2 + (size_t)(m * OSZ + r16) * D_IN + m * DIM + half * BN;
#pragma unroll
            for (int kc = 0; kc < BN / 32; kc++) {
                const int c = kc * 32 + kq * 8;
                short8 hA = *(const short8*)(ldsH + hrow * HSTRIDE + c);
                short8 wb = {0, 0, 0, 0, 0, 0, 0, 0};
                if (r16 < OSZ) {
                    const float* p = w2row + c;
                    wb = cvt8(*(const float4*)p, *(const float4*)(p + 4));
                }
                acc2 = __builtin_amdgcn_mfma_f32_16x16x32_bf16(hA, wb, acc2, 0, 0, 0);
            }
            if (r16 < OSZ) {
#pragma unroll
                for (int reg = 0; reg < 4; reg++) {
                    const int grow = rowBase + hh * 64 + wave * 16 + kq * 4 + reg;
                    atomicAdd(out + (size_t)grow * D_OUT + m * OSZ + r16, acc2[reg]);
                }
            }
        }
    }
}

extern "C" void kernel_launch(void* const* d_in, const int* in_sizes, int n_in,
                              void* d_out, int out_size, void* d_ws, size_t ws_size,
                              hipStream_t stream) {
    const float* x  = (const float*)d_in[0];
    const float* W1 = (const float*)d_in[1];
    const float* b1 = (const float*)d_in[2];
    const float* W2 = (const float*)d_in[3];
    const float* b2 = (const float*)d_in[4];
    float* out = (float*)d_out;

    init_out_kernel<<<dim3(2560), dim3(256), 0, stream>>>(b2, out);

    if (ws_size >= (size_t)NMOD * DIM * DIM * sizeof(ushort)) {   // 4 MB: tier B (bf16 W1 + DMA)
        ushort* w1b = (ushort*)d_ws;
        cvt_w_kernel<<<dim3(2048), dim3(256), 0, stream>>>(W1, w1b);
        fused_kernel<true><<<dim3(1024), dim3(256), 0, stream>>>(x, W1, w1b, b1, W2, b2, out);
    } else {                                                      // tier C: zero workspace
        fused_kernel<false><<<dim3(1024), dim3(256), 0, stream>>>(x, W1, nullptr, b1, W2, b2, out);
    }
}